// Round 6
// baseline (768.061 us; speedup 1.0000x reference)
//
#include <hip/hip_runtime.h>

// ParabolicPool2D — fully register-resident, ZERO LDS / ZERO barriers.
// Probe decomposition: fixed harness floor ~528us; prior kernel ~182us = 63us compute
// + 119us HBM, perfectly SERIAL (barrier-locked phases; hipcc drains vmcnt(0) before
// every s_barrier, so no cross-phase overlap is possible in any LDS-staged form).
// This version removes LDS entirely: each thread loads 9 rows x 4 float4 (16 cols,
// incl. +-3-col horizontal halo; duplicates are L1/L2-served so HBM traffic is
// unchanged), does the vertical 7-tap (symmetric max-plus tree) and horizontal 7-tap
// in registers, and stores 2x float4. No barriers -> waves drift, compiler pipelines
// the 4 independent column groups, memory and VALU overlap freely.
//
// out[b,c,i,j] = max_{u,v} f[b,c,2i+u-3,2j+v-3] + hu[u] + hu[v],  hu[k] = -(k-3)^2/(4t)

#define H 256
#define W 256
#define HO 128
#define WO 128

__device__ __forceinline__ float4 f4max(float4 a, float4 b) {
    return make_float4(fmaxf(a.x, b.x), fmaxf(a.y, b.y), fmaxf(a.z, b.z), fmaxf(a.w, b.w));
}
__device__ __forceinline__ float4 f4adds(float4 a, float s) {
    return make_float4(a.x + s, a.y + s, a.z + s, a.w + s);
}

__global__ __launch_bounds__(256, 3)
void pp_kernel(const float* __restrict__ f, const float* __restrict__ tptr,
               float* __restrict__ out) {
    const int tid = threadIdx.x;
    const int bid = blockIdx.x;
    // 16384 blocks, 8 XCDs, 2048/XCD: bijective swizzle; consecutive lids on one XCD are
    // consecutive 16-row strips of the same plane -> y-halo rows hit that XCD's L2.
    const int lid   = (bid & 7) * 2048 + (bid >> 3);
    const int plane = lid >> 3;          // b*128 + c
    const int strip = lid & 7;
    const int i0    = strip * 16;        // block covers out rows i0..i0+15

    const float tv  = tptr[0];
    const float inv = 1.0f / (4.0f * tv);
    const float h0 = -9.0f * inv, h1 = -4.0f * inv, h2 = -1.0f * inv;  // h3 = 0
    const float NEG = -__builtin_inff();

    const float* __restrict__ fplane = f + (size_t)plane * (H * W);
    float* __restrict__ oplane = out + (size_t)plane * (HO * WO);

    // Thread tile: out rows (i0+2p, i0+2p+1) x out cols 4jg..4jg+3.
    const int p   = tid >> 5;            // 0..7 row-pair
    const int jg  = tid & 31;            // 0..31 col group
    const int gy0 = 2 * (i0 + 2 * p) - 3;        // first of 9 input rows
    const int gxb = 8 * jg - 4;                  // first of 16 input cols (f4-aligned)

    const bool interior = (gy0 >= 0) && (gy0 + 8 <= H - 1);
    float hu[7];
    hu[0] = h0; hu[1] = h1; hu[2] = h2; hu[3] = 0.0f; hu[4] = h2; hu[5] = h1; hu[6] = h0;

    // Vertical pass, per column group g (16 cols = 4 groups), all in registers.
    // vA = out row i0+2p, vB = out row i0+2p+1.
    float4 vA[4], vB[4];
#pragma unroll
    for (int g = 0; g < 4; ++g) {
        const int cx = min(max(gxb + 4 * g, 0), W - 4);   // clamp: always-valid address
        const float* colp = fplane + cx;
        float4 r[9];
#pragma unroll
        for (int k = 0; k < 9; ++k) {
            const int cy = min(max(gy0 + k, 0), H - 1);   // clamp: y-OOB masked via hu
            r[k] = *(const float4*)(colp + cy * W);
        }
        if (interior) {
            vA[g] = f4max(f4max(f4adds(f4max(r[0], r[6]), h0),
                                f4adds(f4max(r[1], r[5]), h1)),
                          f4max(f4adds(f4max(r[2], r[4]), h2), r[3]));
            vB[g] = f4max(f4max(f4adds(f4max(r[2], r[8]), h0),
                                f4adds(f4max(r[3], r[7]), h1)),
                          f4max(f4adds(f4max(r[4], r[6]), h2), r[5]));
        } else {
            float4 a = make_float4(NEG, NEG, NEG, NEG);
            float4 b = make_float4(NEG, NEG, NEG, NEG);
#pragma unroll
            for (int u = 0; u < 7; ++u) {
                const int gyA = gy0 + u;
                const int gyB = gy0 + 2 + u;
                const float hA = (gyA >= 0 && gyA < H) ? hu[u] : NEG;
                const float hB = (gyB >= 0 && gyB < H) ? hu[u] : NEG;
                a = f4max(a, f4adds(r[u], hA));
                b = f4max(b, f4adds(r[u + 2], hB));
            }
            vA[g] = a; vB[g] = b;
        }
    }

    // x-edge masking: group 0 of jg==0 is cols [-4,-1]; group 3 of jg==31 is cols [256,259].
    if (jg == 0)  { vA[0] = make_float4(NEG, NEG, NEG, NEG); vB[0] = vA[0]; }
    if (jg == 31) { vA[3] = make_float4(NEG, NEG, NEG, NEG); vB[3] = vA[3]; }

    // Horizontal pass from registers: out col j = 4jg+dd needs v raw idx [2dd+1, 2dd+7]
    // (raw idx i = input col gxb+i).
    {
        const float sA[16] = {vA[0].x, vA[0].y, vA[0].z, vA[0].w, vA[1].x, vA[1].y, vA[1].z, vA[1].w,
                              vA[2].x, vA[2].y, vA[2].z, vA[2].w, vA[3].x, vA[3].y, vA[3].z, vA[3].w};
        const float sB[16] = {vB[0].x, vB[0].y, vB[0].z, vB[0].w, vB[1].x, vB[1].y, vB[1].z, vB[1].w,
                              vB[2].x, vB[2].y, vB[2].z, vB[2].w, vB[3].x, vB[3].y, vB[3].z, vB[3].w};
        float4 oA, oB;
        float* opA = (float*)&oA;
        float* opB = (float*)&oB;
#pragma unroll
        for (int dd = 0; dd < 4; ++dd) {
            const float a0 = fmaxf(sA[2 * dd + 1], sA[2 * dd + 7]) + h0;
            const float a1 = fmaxf(sA[2 * dd + 2], sA[2 * dd + 6]) + h1;
            const float a2 = fmaxf(sA[2 * dd + 3], sA[2 * dd + 5]) + h2;
            opA[dd] = fmaxf(fmaxf(a0, a1), fmaxf(a2, sA[2 * dd + 4]));
            const float b0 = fmaxf(sB[2 * dd + 1], sB[2 * dd + 7]) + h0;
            const float b1 = fmaxf(sB[2 * dd + 2], sB[2 * dd + 6]) + h1;
            const float b2 = fmaxf(sB[2 * dd + 3], sB[2 * dd + 5]) + h2;
            opB[dd] = fmaxf(fmaxf(b0, b1), fmaxf(b2, sB[2 * dd + 4]));
        }
        const int orow = i0 + 2 * p;
        *(float4*)(oplane + (size_t)orow * WO + 4 * jg)       = oA;
        *(float4*)(oplane + (size_t)(orow + 1) * WO + 4 * jg) = oB;
    }
}

extern "C" void kernel_launch(void* const* d_in, const int* in_sizes, int n_in,
                              void* d_out, int out_size, void* d_ws, size_t ws_size,
                              hipStream_t stream) {
    const float* f = (const float*)d_in[0];
    const float* t = (const float*)d_in[1];
    float* out = (float*)d_out;
    // 2048 planes x 8 strips, 256 threads = 8 row-pairs x 32 col-groups (8 outputs/thread)
    pp_kernel<<<dim3(2048 * 8), dim3(256), 0, stream>>>(f, t, out);
}